// Round 4
// baseline (449.008 us; speedup 1.0000x reference)
//
#include <hip/hip_runtime.h>
#include <stdint.h>

typedef __bf16 bf16;
typedef __bf16 bf16x8 __attribute__((ext_vector_type(8)));
typedef __bf16 bf16x4 __attribute__((ext_vector_type(4)));
typedef float f32x4 __attribute__((ext_vector_type(4)));

constexpr int NB   = 32;
constexpr int CIN  = 1024;
constexpr int CB   = 256;
constexpr int COUT = 1024;
constexpr int HW   = 784;
constexpr int WIMG = 28;
constexpr int PW   = 30;    // padded width (28+2)
constexpr int PHW  = 900;   // padded pixels per image (30*30)

typedef const __attribute__((address_space(1))) void GV;
typedef __attribute__((address_space(3))) void LV;

// async global->LDS, 16B/lane. LDS dest = uniform base + lane*16 (HW rule);
// global src is per-lane (gather). AMDGPU addrspacecast flat->local = low 32 bits.
__device__ __forceinline__ void gl16(const void* g, void* l) {
  __builtin_amdgcn_global_load_lds((GV*)(uintptr_t)g,
                                   (LV*)(uint32_t)(uintptr_t)l, 16, 0, 0);
}

// ---------------- zero padded o1p buffer (border must be 0; ws re-poisoned each call)
__global__ __launch_bounds__(256) void k_zero(uint4* __restrict__ p, int n) {
  int i = blockIdx.x * 256 + threadIdx.x;
  if (i < n) { uint4 z; z.x = z.y = z.z = z.w = 0u; p[i] = z; }
}

// ---------------- x: fp32 NCHW -> bf16 NHWC (per batch: 1024 x 784 -> 784 x 1024)
__global__ __launch_bounds__(256) void k_transpose(const float* __restrict__ x,
                                                   bf16* __restrict__ xT) {
  __shared__ bf16 tile[64][73];
  const int nb = blockIdx.z;
  const int p0 = blockIdx.x * 64;   // 13
  const int c0 = blockIdx.y * 64;   // 16
  const int tid = threadIdx.x;
#pragma unroll
  for (int it = 0; it < 4; ++it) {
    int idx = tid + it * 256;
    int row = idx >> 4, c4 = idx & 15;
    int p = p0 + c4 * 4;
    if (p < HW) {
      float4 v = *reinterpret_cast<const float4*>(x + (nb * CIN + c0 + row) * HW + p);
      tile[row][c4 * 4 + 0] = (bf16)v.x;
      tile[row][c4 * 4 + 1] = (bf16)v.y;
      tile[row][c4 * 4 + 2] = (bf16)v.z;
      tile[row][c4 * 4 + 3] = (bf16)v.w;
    }
  }
  __syncthreads();
#pragma unroll
  for (int it = 0; it < 2; ++it) {
    int idx = tid + it * 256;
    int pr = idx >> 3, c8 = idx & 7;
    if (p0 + pr < HW) {
      bf16x8 v;
#pragma unroll
      for (int j = 0; j < 8; ++j) v[j] = tile[c8 * 8 + j][pr];
      *reinterpret_cast<bf16x8*>(xT + (nb * HW + p0 + pr) * CIN + c0 + c8 * 8) = v;
    }
  }
}

// ---------------- w2: fp32 [co][ci][3][3] -> bf16 [co][rs][ci]
__global__ __launch_bounds__(256) void k_w2r(const float* __restrict__ w2,
                                             bf16* __restrict__ w2r) {
  int i = blockIdx.x * 256 + threadIdx.x;
  if (i < CB * 9 * CB) {
    int ci = i & 255;
    int t = i >> 8;
    int rs = t % 9;
    int co = t / 9;
    w2r[i] = (bf16)w2[(co * CB + ci) * 9 + rs];
  }
}

// ---------------- fp32 -> bf16 cast
__global__ __launch_bounds__(256) void k_cast(const float* __restrict__ a,
                                              bf16* __restrict__ o, int n) {
  int i = (blockIdx.x * 256 + threadIdx.x) * 4;
  if (i < n) {
    float4 v = *reinterpret_cast<const float4*>(a + i);
    bf16x4 w;
    w[0] = (bf16)v.x; w[1] = (bf16)v.y; w[2] = (bf16)v.z; w[3] = (bf16)v.w;
    *reinterpret_cast<bf16x4*>(o + i) = w;
  }
}

// ---------------- residual epilogue: out = relu(y + x), y bf16 with SAME
// linearization as out (NCHW). Pure stream: 8B + 16B in, 16B out per thread-iter.
// 1568 blocks * 256 thr * 16 iters == 6,422,528 float4 == 25,690,112 floats exactly.
__global__ __launch_bounds__(256) void k_resid(const bf16* __restrict__ y,
                                               const float* __restrict__ x,
                                               float* __restrict__ out) {
  const int stride = 1568 * 256;
  int i = blockIdx.x * 256 + threadIdx.x;
#pragma unroll 4
  for (int it = 0; it < 16; ++it, i += stride) {
    bf16x4 yv = *reinterpret_cast<const bf16x4*>(y + (size_t)i * 4);
    float4 xv = *reinterpret_cast<const float4*>(x + (size_t)i * 4);
    float4 o;
    o.x = fmaxf((float)yv[0] + xv.x, 0.f);
    o.y = fmaxf((float)yv[1] + xv.y, 0.f);
    o.z = fmaxf((float)yv[2] + xv.z, 0.f);
    o.w = fmaxf((float)yv[3] + xv.w, 0.f);
    *reinterpret_cast<float4*>(out + (size_t)i * 4) = o;
  }
}

// =====================================================================
// conv1/conv2 GEMM (this round): block = 256 thr (4 waves 2x2), block tile
// 64(M) x 128(N), wave tile 32x64 (2x4 frags 16x16x32), BK=128.
// Rationale: both were serialization-bound (conv2: 75us, MFMA 15%, HBM 12%,
// occ 15%, grid 392 = 1.5 blk/CU). BK=128 halves the number of serial
// K-step round-trips; M-split 64 doubles the grid (784 = 3 blk/CU) so
// independent blocks interleave round-trips. A staging volume UNCHANGED
// (unlike r2's 64x64 failure); only L2-resident B is re-staged.
// LDS 48KB = A 16 groups of 1KB | B 32 groups of 1KB; group g=(rowgrp,kc):
// rows rowgrp*16+l16, k = kc*32+quad*8 -> ds_read_b128 at base+lane*16
// (conflict-free), gl16 staging lane-linear. Waves 0-1 stage A (8 gl16),
// waves 2-3 stage B (16 gl16). Serial stage->sync->compute->sync loop.
// =====================================================================

// ---------------- conv1: o1p[pad(m)][co] = relu(s1*xT[m][:]·w1[co][:]+b1)
__global__ __launch_bounds__(256, 3) void k_conv1(const bf16* __restrict__ xT,
                                                  const bf16* __restrict__ w1,
                                                  const float* __restrict__ s1,
                                                  const float* __restrict__ b1,
                                                  bf16* __restrict__ o1p) {
  __shared__ char smem[49152];                 // A 16KB | B 32KB
  char* const As = smem;
  char* const Bs = smem + 16384;
  const int tid = threadIdx.x, wave = tid >> 6, lane = tid & 63;
  const int quad = lane >> 4, l16 = lane & 15;
  const int wr = wave >> 1, wc = wave & 1;
  const int Mt = blockIdx.x, Nt = blockIdx.y;
  const bool isA = (wave < 2);

  const bf16* gb[16];
  int lbo;
  if (isA) {
    lbo = wave * 8192;                         // A groups wave*8 .. +7
#pragma unroll
    for (int i = 0; i < 8; ++i) {
      int ga = wave * 8 + i;
      int m = Mt * 64 + (ga >> 2) * 16 + l16;
      gb[i] = xT + (size_t)m * CIN + (ga & 3) * 32 + quad * 8;
    }
  } else {
    lbo = 16384 + (wave - 2) * 16384;          // B groups (wave-2)*16 .. +15
#pragma unroll
    for (int i = 0; i < 16; ++i) {
      int gk = (wave - 2) * 16 + i;
      int n = Nt * 128 + (gk >> 2) * 16 + l16;
      gb[i] = w1 + (size_t)n * CIN + (gk & 3) * 32 + quad * 8;
    }
  }

  f32x4 acc[2][4];
#pragma unroll
  for (int i = 0; i < 2; ++i)
#pragma unroll
    for (int j = 0; j < 4; ++j) acc[i][j] = {0.f, 0.f, 0.f, 0.f};

  const int lo = lane * 16;
  for (int s = 0; s < CIN / 128; ++s) {        // 8 steps
    if (isA) {
#pragma unroll
      for (int i = 0; i < 8; ++i) gl16(gb[i] + s * 128, smem + lbo + i * 1024);
    } else {
#pragma unroll
      for (int i = 0; i < 16; ++i) gl16(gb[i] + s * 128, smem + lbo + i * 1024);
    }
    __syncthreads();
#pragma unroll
    for (int h = 0; h < 4; ++h) {
      bf16x8 a[2], b[4];
#pragma unroll
      for (int mi = 0; mi < 2; ++mi)
        a[mi] = *(const bf16x8*)(As + (((wr * 2 + mi) * 4 + h) * 1024) + lo);
#pragma unroll
      for (int ni = 0; ni < 4; ++ni)
        b[ni] = *(const bf16x8*)(Bs + (((wc * 4 + ni) * 4 + h) * 1024) + lo);
#pragma unroll
      for (int mi = 0; mi < 2; ++mi)
#pragma unroll
        for (int ni = 0; ni < 4; ++ni)
          acc[mi][ni] = __builtin_amdgcn_mfma_f32_16x16x32_bf16(a[mi], b[ni], acc[mi][ni], 0, 0, 0);
    }
    __syncthreads();
  }

  float sv[4], bv[4];
  const int nb0 = Nt * 128 + wc * 64;
#pragma unroll
  for (int ni = 0; ni < 4; ++ni) { int n = nb0 + ni * 16 + l16; sv[ni] = s1[n]; bv[ni] = b1[n]; }
#pragma unroll
  for (int mi = 0; mi < 2; ++mi)
#pragma unroll
    for (int r = 0; r < 4; ++r) {
      int m = Mt * 64 + wr * 32 + mi * 16 + quad * 4 + r;
      int nbi = m / HW, p = m - nbi * HW;
      int hh = p / WIMG, ww = p - hh * WIMG;
      bf16* dst = o1p + ((size_t)nbi * PHW + (hh + 1) * PW + (ww + 1)) * CB;
#pragma unroll
      for (int ni = 0; ni < 4; ++ni) {
        int n = nb0 + ni * 16 + l16;
        dst[n] = (bf16)fmaxf(acc[mi][ni][r] * sv[ni] + bv[ni], 0.f);
      }
    }
}

// ---------------- conv2: 3x3 SAME over padded o1p, K = 9*256, 18 BK128 steps
__global__ __launch_bounds__(256, 3) void k_conv2(const bf16* __restrict__ o1p,
                                                  const bf16* __restrict__ w2r,
                                                  const float* __restrict__ s2,
                                                  const float* __restrict__ b2,
                                                  bf16* __restrict__ o2) {
  __shared__ char smem[49152];
  char* const As = smem;
  char* const Bs = smem + 16384;
  const int tid = threadIdx.x, wave = tid >> 6, lane = tid & 63;
  const int quad = lane >> 4, l16 = lane & 15;
  const int wr = wave >> 1, wc = wave & 1;
  const int Mt = blockIdx.x, Nt = blockIdx.y;
  const bool isA = (wave < 2);

  const bf16* gb[16];
  int lbo;
  if (isA) {
    lbo = wave * 8192;
#pragma unroll
    for (int i = 0; i < 8; ++i) {
      int ga = wave * 8 + i;
      int m = Mt * 64 + (ga >> 2) * 16 + l16;
      int nbi = m / HW, p = m - nbi * HW;
      int hh = p / WIMG, ww = p - hh * WIMG;
      int pp = nbi * PHW + (hh + 1) * PW + (ww + 1);
      gb[i] = o1p + (size_t)pp * CB + (ga & 3) * 32 + quad * 8;
    }
  } else {
    lbo = 16384 + (wave - 2) * 16384;
#pragma unroll
    for (int i = 0; i < 16; ++i) {
      int gk = (wave - 2) * 16 + i;
      int n = Nt * 128 + (gk >> 2) * 16 + l16;
      gb[i] = w2r + (size_t)n * (9 * CB) + (gk & 3) * 32 + quad * 8;
    }
  }

  f32x4 acc[2][4];
#pragma unroll
  for (int i = 0; i < 2; ++i)
#pragma unroll
    for (int j = 0; j < 4; ++j) acc[i][j] = {0.f, 0.f, 0.f, 0.f};

  const int lo = lane * 16;
  for (int s = 0; s < 18; ++s) {               // 18 steps of BK=128 (half-tap)
    int rs = s >> 1;
    int aoff = ((rs / 3) - 1) * PW + (rs % 3) - 1;   // spatial halo offset (padded px)
    if (isA) {
      int soff = aoff * CB + (s & 1) * 128;
#pragma unroll
      for (int i = 0; i < 8; ++i) gl16(gb[i] + soff, smem + lbo + i * 1024);
    } else {
      int soff = s * 128;
#pragma unroll
      for (int i = 0; i < 16; ++i) gl16(gb[i] + soff, smem + lbo + i * 1024);
    }
    __syncthreads();
#pragma unroll
    for (int h = 0; h < 4; ++h) {
      bf16x8 a[2], b[4];
#pragma unroll
      for (int mi = 0; mi < 2; ++mi)
        a[mi] = *(const bf16x8*)(As + (((wr * 2 + mi) * 4 + h) * 1024) + lo);
#pragma unroll
      for (int ni = 0; ni < 4; ++ni)
        b[ni] = *(const bf16x8*)(Bs + (((wc * 4 + ni) * 4 + h) * 1024) + lo);
#pragma unroll
      for (int mi = 0; mi < 2; ++mi)
#pragma unroll
        for (int ni = 0; ni < 4; ++ni)
          acc[mi][ni] = __builtin_amdgcn_mfma_f32_16x16x32_bf16(a[mi], b[ni], acc[mi][ni], 0, 0, 0);
    }
    __syncthreads();
  }

  float sv[4], bv[4];
  const int nb0 = Nt * 128 + wc * 64;
#pragma unroll
  for (int ni = 0; ni < 4; ++ni) { int n = nb0 + ni * 16 + l16; sv[ni] = s2[n]; bv[ni] = b2[n]; }
#pragma unroll
  for (int mi = 0; mi < 2; ++mi)
#pragma unroll
    for (int r = 0; r < 4; ++r) {
      int m = Mt * 64 + wr * 32 + mi * 16 + quad * 4 + r;
      bf16* dst = o2 + (size_t)m * CB;
#pragma unroll
      for (int ni = 0; ni < 4; ++ni) {
        int n = nb0 + ni * 16 + l16;
        dst[n] = (bf16)fmaxf(acc[mi][ni][r] * sv[ni] + bv[ni], 0.f);
      }
    }
}

// ---------------- conv3g: y[nb][co][p] = s3*o2[p][:]·w3[co][:]+b3 (bf16, no relu,
// no residual — those move to k_resid). y layout == out layout (NCHW linear).
__global__ __launch_bounds__(256, 2) void k_conv3g(const bf16* __restrict__ o2,
                                                   const bf16* __restrict__ w3,
                                                   const float* __restrict__ s3,
                                                   const float* __restrict__ b3,
                                                   bf16* __restrict__ y) {
  __shared__ char smem[32768];
  char* const As = smem;
  char* const Bs = smem + 16384;
  const int tid = threadIdx.x, wave = tid >> 6, lane = tid & 63;
  const int quad = lane >> 4, l16 = lane & 15;
  const int wr = wave >> 1, wc = wave & 1;
  const int Mt = blockIdx.x, Nt = blockIdx.y, nbz = blockIdx.z;

  const bf16* gb[8];
  char* lb;
  if (wave < 2) {
    lb = As + wave * 8192;
#pragma unroll
    for (int i = 0; i < 8; ++i) {
      int g = wave * 8 + i;
      int m = Mt * 128 + (g >> 1) * 16 + l16;               // co < 1024
      gb[i] = w3 + (size_t)m * CB + ((g & 1) * 4 + quad) * 8;
    }
  } else {
    lb = Bs + (wave - 2) * 8192;
#pragma unroll
    for (int i = 0; i < 8; ++i) {
      int g = (wave - 2) * 8 + i;
      int p = Nt * 128 + (g >> 1) * 16 + l16;
      int pc = min(p, HW - 1);                              // clamp; never stored
      gb[i] = o2 + ((size_t)nbz * HW + pc) * CB + ((g & 1) * 4 + quad) * 8;
    }
  }

  f32x4 acc[4][4];
#pragma unroll
  for (int i = 0; i < 4; ++i)
#pragma unroll
    for (int j = 0; j < 4; ++j) acc[i][j] = {0.f, 0.f, 0.f, 0.f};

  const int lo = lane * 16;
  for (int s = 0; s < CB / 64; ++s) {
#pragma unroll
    for (int i = 0; i < 8; ++i) gl16(gb[i] + s * 64, lb + i * 1024);
    __syncthreads();
    bf16x8 a[4][2], b[4][2];
#pragma unroll
    for (int mi = 0; mi < 4; ++mi)
#pragma unroll
      for (int h = 0; h < 2; ++h)
        a[mi][h] = *(const bf16x8*)(As + (((wr * 4 + mi) * 2 + h) * 1024) + lo);
#pragma unroll
    for (int ni = 0; ni < 4; ++ni)
#pragma unroll
      for (int h = 0; h < 2; ++h)
        b[ni][h] = *(const bf16x8*)(Bs + (((wc * 4 + ni) * 2 + h) * 1024) + lo);
#pragma unroll
    for (int h = 0; h < 2; ++h)
#pragma unroll
      for (int mi = 0; mi < 4; ++mi)
#pragma unroll
        for (int ni = 0; ni < 4; ++ni)
          acc[mi][ni] = __builtin_amdgcn_mfma_f32_16x16x32_bf16(a[mi][h], b[ni][h], acc[mi][ni], 0, 0, 0);
    __syncthreads();
  }

#pragma unroll
  for (int mi = 0; mi < 4; ++mi)
#pragma unroll
    for (int r = 0; r < 4; ++r) {
      int m = Mt * 128 + wr * 64 + mi * 16 + quad * 4 + r;  // co
      float sv = s3[m], bvv = b3[m];
      bf16* yr = y + ((size_t)nbz * COUT + m) * HW;
#pragma unroll
      for (int ni = 0; ni < 4; ++ni) {
        int n = Nt * 128 + wc * 64 + ni * 16 + l16;
        if (n < HW) yr[n] = (bf16)(acc[mi][ni][r] * sv + bvv);
      }
    }
}

extern "C" void kernel_launch(void* const* d_in, const int* in_sizes, int n_in,
                              void* d_out, int out_size, void* d_ws, size_t ws_size,
                              hipStream_t stream) {
  const float* x  = (const float*)d_in[0];
  const float* w1 = (const float*)d_in[1];
  const float* w2 = (const float*)d_in[2];
  const float* w3 = (const float*)d_in[3];
  const float* s1 = (const float*)d_in[4];
  const float* b1 = (const float*)d_in[5];
  const float* s2 = (const float*)d_in[6];
  const float* b2 = (const float*)d_in[7];
  const float* s3 = (const float*)d_in[8];
  const float* b3 = (const float*)d_in[9];
  float* out = (float*)d_out;

  char* ws = (char*)d_ws;
  // layout (bytes):
  //   xT/o2 share [0, 51,380,224) — xT dead before conv2 writes o2 (o2 = 12.8 MB at 0).
  //   y (bf16, out-linearized, 51,380,224 B) at 12,845,056 — overlaps o1p region,
  //     but o1p is dead after conv2 and y is written by conv3g (after conv2). No
  //     overlap with o2 [0,12.8M) or w2r (66.1M+).
  //   o1p (padded bf16 NHWC 32x900x256) at 51,380,224 (14,745,600 B)
  //   w2r at 66,125,824 (1,179,648) | w1b at 67,305,472 (524,288) | w3b at 67,829,760 (524,288)
  bf16* xT  = (bf16*)(ws);
  bf16* o2  = (bf16*)(ws);
  bf16* y   = (bf16*)(ws + 12845056);
  bf16* o1p = (bf16*)(ws + 51380224);
  bf16* w2r = (bf16*)(ws + 66125824);
  bf16* w1b = (bf16*)(ws + 67305472);
  bf16* w3b = (bf16*)(ws + 67829760);

  k_zero<<<dim3(3600, 1, 1), 256, 0, stream>>>((uint4*)o1p, 921600);
  k_transpose<<<dim3(13, 16, NB), 256, 0, stream>>>(x, xT);
  k_w2r<<<dim3(2304, 1, 1), 256, 0, stream>>>(w2, w2r);
  k_cast<<<dim3(256, 1, 1), 256, 0, stream>>>(w1, w1b, CB * CIN);
  k_cast<<<dim3(256, 1, 1), 256, 0, stream>>>(w3, w3b, COUT * CB);
  k_conv1<<<dim3(392, 2, 1), 256, 0, stream>>>(xT, w1b, s1, b1, o1p);
  k_conv2<<<dim3(392, 2, 1), 256, 0, stream>>>(o1p, w2r, s2, b2, o2);
  k_conv3g<<<dim3(8, 7, NB), 256, 0, stream>>>(o2, w3b, s3, b3, y);
  k_resid<<<dim3(1568, 1, 1), 256, 0, stream>>>(y, x, out);
}

// Round 5
// 401.505 us; speedup vs baseline: 1.1183x; 1.1183x over previous
//
#include <hip/hip_runtime.h>
#include <stdint.h>

typedef __bf16 bf16;
typedef __bf16 bf16x8 __attribute__((ext_vector_type(8)));
typedef __bf16 bf16x4 __attribute__((ext_vector_type(4)));
typedef float f32x4 __attribute__((ext_vector_type(4)));

constexpr int NB   = 32;
constexpr int CIN  = 1024;
constexpr int CB   = 256;
constexpr int COUT = 1024;
constexpr int HW   = 784;
constexpr int WIMG = 28;
constexpr int PW   = 30;    // padded width (28+2)
constexpr int PHW  = 900;   // padded pixels per image (30*30)

typedef const __attribute__((address_space(1))) void GV;
typedef __attribute__((address_space(3))) void LV;

// async global->LDS, 16B/lane (used by conv3g only now)
__device__ __forceinline__ void gl16(const void* g, void* l) {
  __builtin_amdgcn_global_load_lds((GV*)(uintptr_t)g,
                                   (LV*)(uint32_t)(uintptr_t)l, 16, 0, 0);
}

// raw barrier with compiler memory fences on both sides; does NOT drain vmcnt
// (prefetch loads stay in flight across it — the whole point).
__device__ __forceinline__ void bar() {
  asm volatile("" ::: "memory");
  __builtin_amdgcn_s_barrier();
  asm volatile("" ::: "memory");
}
// barrier that first drains this wave's LDS writes (lgkmcnt only, not vmcnt)
__device__ __forceinline__ void bar_lds() {
  asm volatile("s_waitcnt lgkmcnt(0)" ::: "memory");
  __builtin_amdgcn_s_barrier();
  asm volatile("" ::: "memory");
}

// ---------------- zero padded o1p buffer (border must be 0; ws re-poisoned each call)
__global__ __launch_bounds__(256) void k_zero(uint4* __restrict__ p, int n) {
  int i = blockIdx.x * 256 + threadIdx.x;
  if (i < n) { uint4 z; z.x = z.y = z.z = z.w = 0u; p[i] = z; }
}

// ---------------- x: fp32 NCHW -> bf16 NHWC (per batch: 1024 x 784 -> 784 x 1024)
__global__ __launch_bounds__(256) void k_transpose(const float* __restrict__ x,
                                                   bf16* __restrict__ xT) {
  __shared__ bf16 tile[64][73];
  const int nb = blockIdx.z;
  const int p0 = blockIdx.x * 64;   // 13
  const int c0 = blockIdx.y * 64;   // 16
  const int tid = threadIdx.x;
#pragma unroll
  for (int it = 0; it < 4; ++it) {
    int idx = tid + it * 256;
    int row = idx >> 4, c4 = idx & 15;
    int p = p0 + c4 * 4;
    if (p < HW) {
      float4 v = *reinterpret_cast<const float4*>(x + (nb * CIN + c0 + row) * HW + p);
      tile[row][c4 * 4 + 0] = (bf16)v.x;
      tile[row][c4 * 4 + 1] = (bf16)v.y;
      tile[row][c4 * 4 + 2] = (bf16)v.z;
      tile[row][c4 * 4 + 3] = (bf16)v.w;
    }
  }
  __syncthreads();
#pragma unroll
  for (int it = 0; it < 2; ++it) {
    int idx = tid + it * 256;
    int pr = idx >> 3, c8 = idx & 7;
    if (p0 + pr < HW) {
      bf16x8 v;
#pragma unroll
      for (int j = 0; j < 8; ++j) v[j] = tile[c8 * 8 + j][pr];
      *reinterpret_cast<bf16x8*>(xT + (nb * HW + p0 + pr) * CIN + c0 + c8 * 8) = v;
    }
  }
}

// ---------------- w2: fp32 [co][ci][3][3] -> bf16 [co][rs][ci]
__global__ __launch_bounds__(256) void k_w2r(const float* __restrict__ w2,
                                             bf16* __restrict__ w2r) {
  int i = blockIdx.x * 256 + threadIdx.x;
  if (i < CB * 9 * CB) {
    int ci = i & 255;
    int t = i >> 8;
    int rs = t % 9;
    int co = t / 9;
    w2r[i] = (bf16)w2[(co * CB + ci) * 9 + rs];
  }
}

// ---------------- fp32 -> bf16 cast
__global__ __launch_bounds__(256) void k_cast(const float* __restrict__ a,
                                              bf16* __restrict__ o, int n) {
  int i = (blockIdx.x * 256 + threadIdx.x) * 4;
  if (i < n) {
    float4 v = *reinterpret_cast<const float4*>(a + i);
    bf16x4 w;
    w[0] = (bf16)v.x; w[1] = (bf16)v.y; w[2] = (bf16)v.z; w[3] = (bf16)v.w;
    *reinterpret_cast<bf16x4*>(o + i) = w;
  }
}

// ---------------- residual epilogue: out = relu(y + x), y bf16 with SAME
// linearization as out (NCHW). Pure stream.
__global__ __launch_bounds__(256) void k_resid(const bf16* __restrict__ y,
                                               const float* __restrict__ x,
                                               float* __restrict__ out) {
  const int stride = 1568 * 256;
  int i = blockIdx.x * 256 + threadIdx.x;
#pragma unroll 4
  for (int it = 0; it < 16; ++it, i += stride) {
    bf16x4 yv = *reinterpret_cast<const bf16x4*>(y + (size_t)i * 4);
    float4 xv = *reinterpret_cast<const float4*>(x + (size_t)i * 4);
    float4 o;
    o.x = fmaxf((float)yv[0] + xv.x, 0.f);
    o.y = fmaxf((float)yv[1] + xv.y, 0.f);
    o.z = fmaxf((float)yv[2] + xv.z, 0.f);
    o.w = fmaxf((float)yv[3] + xv.w, 0.f);
    *reinterpret_cast<float4*>(out + (size_t)i * 4) = o;
  }
}

// =====================================================================
// conv1/conv2 GEMM: round-3 geometry exactly (block 256 thr / 4 waves 2x2,
// tile 128x128, wave tile 64x64, BK=64, LDS 32KB = A 16KB | B 16KB, fragment-
// order groups of 1KB, ds ops at base+lane*16, conflict-free). ONE change:
// T14 reg-staging pipeline. Per step: prefetch step s+1 global->regs (issued
// FIRST), ds_write step-s regs->LDS, bar_lds (lgkmcnt-only drain + barrier,
// vmcnt NOT drained -> prefetch stays in flight across barriers), compute,
// bar. Two reg sets (rA/rB, 64 VGPR) avoid WAR serialization. The counted
// vmcnt before ds_write is compiler-inserted from register deps.
// =====================================================================

#define GEMM_COMPUTE()                                                          \
  {                                                                             \
    bf16x8 a[4][2], b[4][2];                                                    \
    _Pragma("unroll")                                                           \
    for (int mi = 0; mi < 4; ++mi)                                              \
      _Pragma("unroll")                                                         \
      for (int h = 0; h < 2; ++h)                                               \
        a[mi][h] = *(const bf16x8*)(As + (((wr * 4 + mi) * 2 + h) * 1024) + lo);\
    _Pragma("unroll")                                                           \
    for (int ni = 0; ni < 4; ++ni)                                              \
      _Pragma("unroll")                                                         \
      for (int h = 0; h < 2; ++h)                                               \
        b[ni][h] = *(const bf16x8*)(Bs + (((wc * 4 + ni) * 2 + h) * 1024) + lo);\
    _Pragma("unroll")                                                           \
    for (int h = 0; h < 2; ++h)                                                 \
      _Pragma("unroll")                                                         \
      for (int mi = 0; mi < 4; ++mi)                                            \
        _Pragma("unroll")                                                       \
        for (int ni = 0; ni < 4; ++ni)                                          \
          acc[mi][ni] = __builtin_amdgcn_mfma_f32_16x16x32_bf16(                \
              a[mi][h], b[ni][h], acc[mi][ni], 0, 0, 0);                        \
  }

// ---------------- conv1: o1p[pad(m)][co] = relu(s1*xT[m][:]·w1[co][:]+b1)
__global__ __launch_bounds__(256, 2) void k_conv1(const bf16* __restrict__ xT,
                                                  const bf16* __restrict__ w1,
                                                  const float* __restrict__ s1,
                                                  const float* __restrict__ b1,
                                                  bf16* __restrict__ o1p) {
  __shared__ char smem[32768];
  char* const As = smem;
  char* const Bs = smem + 16384;
  const int tid = threadIdx.x, wave = tid >> 6, lane = tid & 63;
  const int quad = lane >> 4, l16 = lane & 15;
  const int wr = wave >> 1, wc = wave & 1;
  const int Mt = blockIdx.x, Nt = blockIdx.y;

  const bf16* gb[8];
  char* lw;
  if (wave < 2) {
    lw = As + wave * 8192;
#pragma unroll
    for (int i = 0; i < 8; ++i) {
      int g = wave * 8 + i;
      int m = Mt * 128 + (g >> 1) * 16 + l16;
      gb[i] = xT + (size_t)m * CIN + ((g & 1) * 4 + quad) * 8;
    }
  } else {
    lw = Bs + (wave - 2) * 8192;
#pragma unroll
    for (int i = 0; i < 8; ++i) {
      int g = (wave - 2) * 8 + i;
      int n = Nt * 128 + (g >> 1) * 16 + l16;
      gb[i] = w1 + (size_t)n * CIN + ((g & 1) * 4 + quad) * 8;
    }
  }

  f32x4 acc[4][4];
#pragma unroll
  for (int i = 0; i < 4; ++i)
#pragma unroll
    for (int j = 0; j < 4; ++j) acc[i][j] = {0.f, 0.f, 0.f, 0.f};

  const int lo = lane * 16;
  bf16x8 rA[8], rB[8];
#pragma unroll
  for (int i = 0; i < 8; ++i) rA[i] = *(const bf16x8*)(gb[i]);      // step 0

  for (int s = 0; s < 16; s += 2) {
    // ---- even step s: prefetch s+1 -> rB, write rA, compute
    bar();                                    // prev-step readers done
#pragma unroll
    for (int i = 0; i < 8; ++i) rB[i] = *(const bf16x8*)(gb[i] + (s + 1) * 64);
#pragma unroll
    for (int i = 0; i < 8; ++i) *(bf16x8*)(lw + i * 1024 + lo) = rA[i];
    bar_lds();
    GEMM_COMPUTE();
    // ---- odd step s+1: prefetch s+2 -> rA, write rB, compute
    bar();
    if (s + 2 < 16) {
#pragma unroll
      for (int i = 0; i < 8; ++i) rA[i] = *(const bf16x8*)(gb[i] + (s + 2) * 64);
    }
#pragma unroll
    for (int i = 0; i < 8; ++i) *(bf16x8*)(lw + i * 1024 + lo) = rB[i];
    bar_lds();
    GEMM_COMPUTE();
  }

  float sv[4], bv[4];
  const int nb0 = Nt * 128 + wc * 64;
#pragma unroll
  for (int ni = 0; ni < 4; ++ni) { int n = nb0 + ni * 16 + l16; sv[ni] = s1[n]; bv[ni] = b1[n]; }
#pragma unroll
  for (int mi = 0; mi < 4; ++mi)
#pragma unroll
    for (int r = 0; r < 4; ++r) {
      int m = Mt * 128 + wr * 64 + mi * 16 + quad * 4 + r;
      int nbi = m / HW, p = m - nbi * HW;
      int hh = p / WIMG, ww = p - hh * WIMG;
      bf16* dst = o1p + ((size_t)nbi * PHW + (hh + 1) * PW + (ww + 1)) * CB;
#pragma unroll
      for (int ni = 0; ni < 4; ++ni) {
        int n = nb0 + ni * 16 + l16;
        dst[n] = (bf16)fmaxf(acc[mi][ni][r] * sv[ni] + bv[ni], 0.f);
      }
    }
}

// ---------------- conv2: 3x3 SAME over padded o1p, K = 9*256, 36 BK64 steps
__global__ __launch_bounds__(256, 2) void k_conv2(const bf16* __restrict__ o1p,
                                                  const bf16* __restrict__ w2r,
                                                  const float* __restrict__ s2,
                                                  const float* __restrict__ b2,
                                                  bf16* __restrict__ o2) {
  __shared__ char smem[32768];
  char* const As = smem;
  char* const Bs = smem + 16384;
  const int tid = threadIdx.x, wave = tid >> 6, lane = tid & 63;
  const int quad = lane >> 4, l16 = lane & 15;
  const int wr = wave >> 1, wc = wave & 1;
  const int Mt = blockIdx.x, Nt = blockIdx.y;
  const bool isA = (wave < 2);

  const bf16* gb[8];
  char* lw;
  if (isA) {
    lw = As + wave * 8192;
#pragma unroll
    for (int i = 0; i < 8; ++i) {
      int g = wave * 8 + i;
      int m = Mt * 128 + (g >> 1) * 16 + l16;
      int nbi = m / HW, p = m - nbi * HW;
      int hh = p / WIMG, ww = p - hh * WIMG;
      int pp = nbi * PHW + (hh + 1) * PW + (ww + 1);
      gb[i] = o1p + (size_t)pp * CB + ((g & 1) * 4 + quad) * 8;
    }
  } else {
    lw = Bs + (wave - 2) * 8192;
#pragma unroll
    for (int i = 0; i < 8; ++i) {
      int g = (wave - 2) * 8 + i;
      int n = Nt * 128 + (g >> 1) * 16 + l16;
      gb[i] = w2r + (size_t)n * (9 * CB) + ((g & 1) * 4 + quad) * 8;
    }
  }

  f32x4 acc[4][4];
#pragma unroll
  for (int i = 0; i < 4; ++i)
#pragma unroll
    for (int j = 0; j < 4; ++j) acc[i][j] = {0.f, 0.f, 0.f, 0.f};

  const int lo = lane * 16;
  // per-step element offset into gb
  auto soff_of = [&](int s) -> int {
    int rs = s >> 2;
    int aoff = ((rs / 3) - 1) * PW + (rs % 3) - 1;   // spatial halo offset (padded px)
    return isA ? (aoff * CB + (s & 3) * 64) : (s * 64);
  };

  bf16x8 rA[8], rB[8];
  {
    int o0 = soff_of(0);
#pragma unroll
    for (int i = 0; i < 8; ++i) rA[i] = *(const bf16x8*)(gb[i] + o0);
  }

  for (int s = 0; s < 36; s += 2) {
    // ---- even step s
    bar();
    {
      int o1 = soff_of(s + 1);                       // s+1 <= 35 always
#pragma unroll
      for (int i = 0; i < 8; ++i) rB[i] = *(const bf16x8*)(gb[i] + o1);
    }
#pragma unroll
    for (int i = 0; i < 8; ++i) *(bf16x8*)(lw + i * 1024 + lo) = rA[i];
    bar_lds();
    GEMM_COMPUTE();
    // ---- odd step s+1
    bar();
    if (s + 2 < 36) {
      int o2 = soff_of(s + 2);
#pragma unroll
      for (int i = 0; i < 8; ++i) rA[i] = *(const bf16x8*)(gb[i] + o2);
    }
#pragma unroll
    for (int i = 0; i < 8; ++i) *(bf16x8*)(lw + i * 1024 + lo) = rB[i];
    bar_lds();
    GEMM_COMPUTE();
  }

  float sv[4], bv[4];
  const int nb0 = Nt * 128 + wc * 64;
#pragma unroll
  for (int ni = 0; ni < 4; ++ni) { int n = nb0 + ni * 16 + l16; sv[ni] = s2[n]; bv[ni] = b2[n]; }
#pragma unroll
  for (int mi = 0; mi < 4; ++mi)
#pragma unroll
    for (int r = 0; r < 4; ++r) {
      int m = Mt * 128 + wr * 64 + mi * 16 + quad * 4 + r;
      bf16* dst = o2 + (size_t)m * CB;
#pragma unroll
      for (int ni = 0; ni < 4; ++ni) {
        int n = nb0 + ni * 16 + l16;
        dst[n] = (bf16)fmaxf(acc[mi][ni][r] * sv[ni] + bv[ni], 0.f);
      }
    }
}

// ---------------- conv3g: y[nb][co][p] = s3*o2[p][:]·w3[co][:]+b3 (bf16, no relu,
// no residual — those move to k_resid). y layout == out layout (NCHW linear).
__global__ __launch_bounds__(256, 2) void k_conv3g(const bf16* __restrict__ o2,
                                                   const bf16* __restrict__ w3,
                                                   const float* __restrict__ s3,
                                                   const float* __restrict__ b3,
                                                   bf16* __restrict__ y) {
  __shared__ char smem[32768];
  char* const As = smem;
  char* const Bs = smem + 16384;
  const int tid = threadIdx.x, wave = tid >> 6, lane = tid & 63;
  const int quad = lane >> 4, l16 = lane & 15;
  const int wr = wave >> 1, wc = wave & 1;
  const int Mt = blockIdx.x, Nt = blockIdx.y, nbz = blockIdx.z;

  const bf16* gb[8];
  char* lb;
  if (wave < 2) {
    lb = As + wave * 8192;
#pragma unroll
    for (int i = 0; i < 8; ++i) {
      int g = wave * 8 + i;
      int m = Mt * 128 + (g >> 1) * 16 + l16;               // co < 1024
      gb[i] = w3 + (size_t)m * CB + ((g & 1) * 4 + quad) * 8;
    }
  } else {
    lb = Bs + (wave - 2) * 8192;
#pragma unroll
    for (int i = 0; i < 8; ++i) {
      int g = (wave - 2) * 8 + i;
      int p = Nt * 128 + (g >> 1) * 16 + l16;
      int pc = min(p, HW - 1);                              // clamp; never stored
      gb[i] = o2 + ((size_t)nbz * HW + pc) * CB + ((g & 1) * 4 + quad) * 8;
    }
  }

  f32x4 acc[4][4];
#pragma unroll
  for (int i = 0; i < 4; ++i)
#pragma unroll
    for (int j = 0; j < 4; ++j) acc[i][j] = {0.f, 0.f, 0.f, 0.f};

  const int lo = lane * 16;
  for (int s = 0; s < CB / 64; ++s) {
#pragma unroll
    for (int i = 0; i < 8; ++i) gl16(gb[i] + s * 64, lb + i * 1024);
    __syncthreads();
    GEMM_COMPUTE();
    __syncthreads();
  }

#pragma unroll
  for (int mi = 0; mi < 4; ++mi)
#pragma unroll
    for (int r = 0; r < 4; ++r) {
      int m = Mt * 128 + wr * 64 + mi * 16 + quad * 4 + r;  // co
      float sv = s3[m], bvv = b3[m];
      bf16* yr = y + ((size_t)nbz * COUT + m) * HW;
#pragma unroll
      for (int ni = 0; ni < 4; ++ni) {
        int n = Nt * 128 + wc * 64 + ni * 16 + l16;
        if (n < HW) yr[n] = (bf16)(acc[mi][ni][r] * sv + bvv);
      }
    }
}

extern "C" void kernel_launch(void* const* d_in, const int* in_sizes, int n_in,
                              void* d_out, int out_size, void* d_ws, size_t ws_size,
                              hipStream_t stream) {
  const float* x  = (const float*)d_in[0];
  const float* w1 = (const float*)d_in[1];
  const float* w2 = (const float*)d_in[2];
  const float* w3 = (const float*)d_in[3];
  const float* s1 = (const float*)d_in[4];
  const float* b1 = (const float*)d_in[5];
  const float* s2 = (const float*)d_in[6];
  const float* b2 = (const float*)d_in[7];
  const float* s3 = (const float*)d_in[8];
  const float* b3 = (const float*)d_in[9];
  float* out = (float*)d_out;

  char* ws = (char*)d_ws;
  // layout (bytes):
  //   xT/o2 share [0, 51,380,224) — xT dead before conv2 writes o2 (o2 = 12.8 MB at 0).
  //   y (bf16, out-linearized, 51,380,224 B) at 12,845,056 — overlaps o1p region,
  //     but o1p is dead after conv2 and y is written by conv3g (after conv2).
  //   o1p (padded bf16 NHWC 32x900x256) at 51,380,224 (14,745,600 B)
  //   w2r at 66,125,824 (1,179,648) | w1b at 67,305,472 (524,288) | w3b at 67,829,760 (524,288)
  bf16* xT  = (bf16*)(ws);
  bf16* o2  = (bf16*)(ws);
  bf16* y   = (bf16*)(ws + 12845056);
  bf16* o1p = (bf16*)(ws + 51380224);
  bf16* w2r = (bf16*)(ws + 66125824);
  bf16* w1b = (bf16*)(ws + 67305472);
  bf16* w3b = (bf16*)(ws + 67829760);

  k_zero<<<dim3(3600, 1, 1), 256, 0, stream>>>((uint4*)o1p, 921600);
  k_transpose<<<dim3(13, 16, NB), 256, 0, stream>>>(x, xT);
  k_w2r<<<dim3(2304, 1, 1), 256, 0, stream>>>(w2, w2r);
  k_cast<<<dim3(256, 1, 1), 256, 0, stream>>>(w1, w1b, CB * CIN);
  k_cast<<<dim3(256, 1, 1), 256, 0, stream>>>(w3, w3b, COUT * CB);
  k_conv1<<<dim3(196, 2, 1), 256, 0, stream>>>(xT, w1b, s1, b1, o1p);
  k_conv2<<<dim3(196, 2, 1), 256, 0, stream>>>(o1p, w2r, s2, b2, o2);
  k_conv3g<<<dim3(8, 7, NB), 256, 0, stream>>>(o2, w3b, s3, b3, y);
  k_resid<<<dim3(1568, 1, 1), 256, 0, stream>>>(y, x, out);
}

// Round 7
// 374.391 us; speedup vs baseline: 1.1993x; 1.0724x over previous
//
#include <hip/hip_runtime.h>
#include <stdint.h>

typedef __bf16 bf16;
typedef __bf16 bf16x8 __attribute__((ext_vector_type(8)));
typedef __bf16 bf16x4 __attribute__((ext_vector_type(4)));
typedef float f32x4 __attribute__((ext_vector_type(4)));

constexpr int NB   = 32;
constexpr int CIN  = 1024;
constexpr int CB   = 256;
constexpr int COUT = 1024;
constexpr int HW   = 784;
constexpr int WIMG = 28;
constexpr int PW   = 30;    // padded width (28+2)
constexpr int PHW  = 900;   // padded pixels per image (30*30)

typedef const __attribute__((address_space(1))) void GV;
typedef __attribute__((address_space(3))) void LV;

// async global->LDS, 16B/lane. LDS dest = uniform base + lane*16 (HW rule).
__device__ __forceinline__ void gl16(const void* g, void* l) {
  __builtin_amdgcn_global_load_lds((GV*)(uintptr_t)g,
                                   (LV*)(uint32_t)(uintptr_t)l, 16, 0, 0);
}

__device__ __forceinline__ void bar() {
  asm volatile("" ::: "memory");
  __builtin_amdgcn_s_barrier();
  asm volatile("" ::: "memory");
}

// ---------------- zero padded o1p buffer (border must be 0; ws re-poisoned each call)
__global__ __launch_bounds__(256) void k_zero(uint4* __restrict__ p, int n) {
  int i = blockIdx.x * 256 + threadIdx.x;
  if (i < n) { uint4 z; z.x = z.y = z.z = z.w = 0u; p[i] = z; }
}

// ---------------- x: fp32 NCHW -> bf16 NHWC (per batch: 1024 x 784 -> 784 x 1024)
__global__ __launch_bounds__(256) void k_transpose(const float* __restrict__ x,
                                                   bf16* __restrict__ xT) {
  __shared__ bf16 tile[64][73];
  const int nb = blockIdx.z;
  const int p0 = blockIdx.x * 64;   // 13
  const int c0 = blockIdx.y * 64;   // 16
  const int tid = threadIdx.x;
#pragma unroll
  for (int it = 0; it < 4; ++it) {
    int idx = tid + it * 256;
    int row = idx >> 4, c4 = idx & 15;
    int p = p0 + c4 * 4;
    if (p < HW) {
      float4 v = *reinterpret_cast<const float4*>(x + (nb * CIN + c0 + row) * HW + p);
      tile[row][c4 * 4 + 0] = (bf16)v.x;
      tile[row][c4 * 4 + 1] = (bf16)v.y;
      tile[row][c4 * 4 + 2] = (bf16)v.z;
      tile[row][c4 * 4 + 3] = (bf16)v.w;
    }
  }
  __syncthreads();
#pragma unroll
  for (int it = 0; it < 2; ++it) {
    int idx = tid + it * 256;
    int pr = idx >> 3, c8 = idx & 7;
    if (p0 + pr < HW) {
      bf16x8 v;
#pragma unroll
      for (int j = 0; j < 8; ++j) v[j] = tile[c8 * 8 + j][pr];
      *reinterpret_cast<bf16x8*>(xT + (nb * HW + p0 + pr) * CIN + c0 + c8 * 8) = v;
    }
  }
}

// ---------------- w2: fp32 [co][ci][3][3] -> bf16 [co][rs][ci]
__global__ __launch_bounds__(256) void k_w2r(const float* __restrict__ w2,
                                             bf16* __restrict__ w2r) {
  int i = blockIdx.x * 256 + threadIdx.x;
  if (i < CB * 9 * CB) {
    int ci = i & 255;
    int t = i >> 8;
    int rs = t % 9;
    int co = t / 9;
    w2r[i] = (bf16)w2[(co * CB + ci) * 9 + rs];
  }
}

// ---------------- fp32 -> bf16 cast
__global__ __launch_bounds__(256) void k_cast(const float* __restrict__ a,
                                              bf16* __restrict__ o, int n) {
  int i = (blockIdx.x * 256 + threadIdx.x) * 4;
  if (i < n) {
    float4 v = *reinterpret_cast<const float4*>(a + i);
    bf16x4 w;
    w[0] = (bf16)v.x; w[1] = (bf16)v.y; w[2] = (bf16)v.z; w[3] = (bf16)v.w;
    *reinterpret_cast<bf16x4*>(o + i) = w;
  }
}

// ---------------- residual epilogue: out = relu(y + x), y bf16 with SAME
// linearization as out (NCHW). Pure stream.
__global__ __launch_bounds__(256) void k_resid(const bf16* __restrict__ y,
                                               const float* __restrict__ x,
                                               float* __restrict__ out) {
  const int stride = 1568 * 256;
  int i = blockIdx.x * 256 + threadIdx.x;
#pragma unroll 4
  for (int it = 0; it < 16; ++it, i += stride) {
    bf16x4 yv = *reinterpret_cast<const bf16x4*>(y + (size_t)i * 4);
    float4 xv = *reinterpret_cast<const float4*>(x + (size_t)i * 4);
    float4 o;
    o.x = fmaxf((float)yv[0] + xv.x, 0.f);
    o.y = fmaxf((float)yv[1] + xv.y, 0.f);
    o.z = fmaxf((float)yv[2] + xv.z, 0.f);
    o.w = fmaxf((float)yv[3] + xv.w, 0.f);
    *reinterpret_cast<float4*>(out + (size_t)i * 4) = o;
  }
}

// ---- round-3 proven 128x128 GEMM compute (conv1 / conv3g) ----
#define GEMM_COMPUTE()                                                          \
  {                                                                             \
    bf16x8 a[4][2], b[4][2];                                                    \
    _Pragma("unroll")                                                           \
    for (int mi = 0; mi < 4; ++mi)                                              \
      _Pragma("unroll")                                                         \
      for (int h = 0; h < 2; ++h)                                               \
        a[mi][h] = *(const bf16x8*)(As + (((wr * 4 + mi) * 2 + h) * 1024) + lo);\
    _Pragma("unroll")                                                           \
    for (int ni = 0; ni < 4; ++ni)                                              \
      _Pragma("unroll")                                                         \
      for (int h = 0; h < 2; ++h)                                               \
        b[ni][h] = *(const bf16x8*)(Bs + (((wc * 4 + ni) * 2 + h) * 1024) + lo);\
    _Pragma("unroll")                                                           \
    for (int h = 0; h < 2; ++h)                                                 \
      _Pragma("unroll")                                                         \
      for (int mi = 0; mi < 4; ++mi)                                            \
        _Pragma("unroll")                                                       \
        for (int ni = 0; ni < 4; ++ni)                                          \
          acc[mi][ni] = __builtin_amdgcn_mfma_f32_16x16x32_bf16(                \
              a[mi][h], b[ni][h], acc[mi][ni], 0, 0, 0);                        \
  }

// ---------------- conv1: o1p[pad(m)][co] = relu(s1*xT[m][:]·w1[co][:]+b1)
// (round-3 structure verbatim)
__global__ __launch_bounds__(256, 2) void k_conv1(const bf16* __restrict__ xT,
                                                  const bf16* __restrict__ w1,
                                                  const float* __restrict__ s1,
                                                  const float* __restrict__ b1,
                                                  bf16* __restrict__ o1p) {
  __shared__ char smem[32768];
  char* const As = smem;
  char* const Bs = smem + 16384;
  const int tid = threadIdx.x, wave = tid >> 6, lane = tid & 63;
  const int quad = lane >> 4, l16 = lane & 15;
  const int wr = wave >> 1, wc = wave & 1;
  const int Mt = blockIdx.x, Nt = blockIdx.y;

  const bf16* gb[8];
  char* lb;
  if (wave < 2) {
    lb = As + wave * 8192;
#pragma unroll
    for (int i = 0; i < 8; ++i) {
      int g = wave * 8 + i;
      int m = Mt * 128 + (g >> 1) * 16 + l16;
      gb[i] = xT + (size_t)m * CIN + ((g & 1) * 4 + quad) * 8;
    }
  } else {
    lb = Bs + (wave - 2) * 8192;
#pragma unroll
    for (int i = 0; i < 8; ++i) {
      int g = (wave - 2) * 8 + i;
      int n = Nt * 128 + (g >> 1) * 16 + l16;
      gb[i] = w1 + (size_t)n * CIN + ((g & 1) * 4 + quad) * 8;
    }
  }

  f32x4 acc[4][4];
#pragma unroll
  for (int i = 0; i < 4; ++i)
#pragma unroll
    for (int j = 0; j < 4; ++j) acc[i][j] = {0.f, 0.f, 0.f, 0.f};

  const int lo = lane * 16;
  for (int s = 0; s < CIN / 64; ++s) {
#pragma unroll
    for (int i = 0; i < 8; ++i) gl16(gb[i] + s * 64, lb + i * 1024);
    __syncthreads();
    GEMM_COMPUTE();
    __syncthreads();
  }

  float sv[4], bv[4];
  const int nb0 = Nt * 128 + wc * 64;
#pragma unroll
  for (int ni = 0; ni < 4; ++ni) { int n = nb0 + ni * 16 + l16; sv[ni] = s1[n]; bv[ni] = b1[n]; }
#pragma unroll
  for (int mi = 0; mi < 4; ++mi)
#pragma unroll
    for (int r = 0; r < 4; ++r) {
      int m = Mt * 128 + wr * 64 + mi * 16 + quad * 4 + r;
      int nbi = m / HW, p = m - nbi * HW;
      int hh = p / WIMG, ww = p - hh * WIMG;
      bf16* dst = o1p + ((size_t)nbi * PHW + (hh + 1) * PW + (ww + 1)) * CB;
#pragma unroll
      for (int ni = 0; ni < 4; ++ni) {
        int n = nb0 + ni * 16 + l16;
        dst[n] = (bf16)fmaxf(acc[mi][ni][r] * sv[ni] + bv[ni], 0.f);
      }
    }
}

// =====================================================================
// conv2: halo-window LDS. Block tile 112 px (4 image rows) x 128 co,
// 4 waves each N=32 (2 frags) x M=112 (7 frags), acc 7x2.
// K-order: ci-chunk c (0..3) outer, tap t (0..8) inner. Per c: stage the
// 6x30 padded window (contiguous 180 px in o1p, 23KB, XOR-swizzled
// (q8*16)^((wpix&7)<<4) to break the 128B-stride bank conflict) ONCE via
// reg-staged ds_write; per t: gl16-stage B (16KB, L2-resident w2r), drain,
// compute 9 taps by shifted window reads (wpix = bw[mf] + dr*30+dc).
// A-side global traffic drops 9x (231 -> ~41 MB): bytes are the binding
// constraint (all 5 prior structures converge to ~6 TB/s staged BW).
// =====================================================================
__global__ __launch_bounds__(256, 2) void k_conv2(const bf16* __restrict__ o1p,
                                                  const bf16* __restrict__ w2r,
                                                  const float* __restrict__ s2,
                                                  const float* __restrict__ b2,
                                                  bf16* __restrict__ o2) {
  __shared__ __align__(16) char smem[23040 + 16384];
  char* const As = smem;            // window: 180 px x 128B, swizzled
  char* const Bs = smem + 23040;    // B: 16 groups of 1KB (fragment order)
  const int tid = threadIdx.x, wave = tid >> 6, lane = tid & 63;
  const int quad = lane >> 4, l16 = lane & 15;
  const int Mt = blockIdx.x, Nt = blockIdx.y;
  const int nb = Mt / 7, rowblk = Mt % 7;

  // B staging pointers: group g = wave*4+i; rows (g>>1)*16+l16, k (g&1)*32+quad*8
  const bf16* gbB[4];
#pragma unroll
  for (int i = 0; i < 4; ++i) {
    int g = wave * 4 + i;
    int n = Nt * 128 + (g >> 1) * 16 + l16;
    gbB[i] = w2r + (size_t)n * (9 * CB) + (g & 1) * 32 + quad * 8;
  }

  // per-lane window-pixel base per M-fragment: pixel p = mf*16+l16 (4 rows of 28)
  int bw[7];
#pragma unroll
  for (int mf = 0; mf < 7; ++mf) {
    int p = mf * 16 + l16;
    bw[mf] = (p / 28) * 30 + (p % 28);
  }
  // window source: contiguous 180 padded pixels starting at padded row rowblk*4
  const char* o1b = (const char*)o1p + (size_t)(nb * PHW + rowblk * 120) * (CB * 2);

  f32x4 acc[7][2];
#pragma unroll
  for (int i = 0; i < 7; ++i)
#pragma unroll
    for (int j = 0; j < 2; ++j) acc[i][j] = {0.f, 0.f, 0.f, 0.f};

  for (int c = 0; c < 4; ++c) {
    bar();                                   // window(c-1) readers done
    // issue B(c, t=0) early (overlaps window loads)
#pragma unroll
    for (int i = 0; i < 4; ++i)
      gl16(gbB[i] + c * 64, Bs + (wave * 4 + i) * 1024);
    // window(c): 180 px x 128B = 1440 slots of 16B; 6 rounds of 256 threads
    bf16x8 wv[6];
#pragma unroll
    for (int j = 0; j < 6; ++j) {
      int slot = j * 256 + tid;
      if (j < 5 || slot < 1440)
        wv[j] = *(const bf16x8*)(o1b + (size_t)(slot >> 3) * 512 + c * 128 + (slot & 7) * 16);
    }
#pragma unroll
    for (int j = 0; j < 6; ++j) {
      int slot = j * 256 + tid;
      if (j < 5 || slot < 1440) {
        int wpix = slot >> 3, q8 = slot & 7;
        *(bf16x8*)(As + wpix * 128 + ((q8 * 16) ^ ((wpix & 7) << 4))) = wv[j];
      }
    }
    asm volatile("s_waitcnt vmcnt(0) lgkmcnt(0)" ::: "memory");
    __builtin_amdgcn_s_barrier();
    asm volatile("" ::: "memory");

#pragma unroll
    for (int t = 0; t < 9; ++t) {
      const int toff = (t / 3) * 30 + (t % 3);
      bf16x8 b[2][2];
#pragma unroll
      for (int ni = 0; ni < 2; ++ni)
#pragma unroll
        for (int h = 0; h < 2; ++h)
          b[ni][h] = *(const bf16x8*)(Bs + (((wave * 2 + ni) * 2 + h) * 1024) + lane * 16);
#pragma unroll
      for (int h = 0; h < 2; ++h) {
        bf16x8 ah[7];
#pragma unroll
        for (int mf = 0; mf < 7; ++mf) {
          int w = bw[mf] + toff;
          ah[mf] = *(const bf16x8*)(As + w * 128 + (((h * 4 + quad) * 16) ^ ((w & 7) << 4)));
        }
#pragma unroll
        for (int mf = 0; mf < 7; ++mf)
#pragma unroll
          for (int ni = 0; ni < 2; ++ni)
            acc[mf][ni] = __builtin_amdgcn_mfma_f32_16x16x32_bf16(ah[mf], b[ni][h], acc[mf][ni], 0, 0, 0);
      }
      if (t < 8) {
        bar();                               // B readers done before overwrite
#pragma unroll
        for (int i = 0; i < 4; ++i)
          gl16(gbB[i] + (t + 1) * 256 + c * 64, Bs + (wave * 4 + i) * 1024);
        asm volatile("s_waitcnt vmcnt(0)" ::: "memory");
        __builtin_amdgcn_s_barrier();
        asm volatile("" ::: "memory");
      }
    }
  }

  float sv[2], bv[2];
  const int nb0 = Nt * 128 + wave * 32;
#pragma unroll
  for (int ni = 0; ni < 2; ++ni) { int n = nb0 + ni * 16 + l16; sv[ni] = s2[n]; bv[ni] = b2[n]; }
#pragma unroll
  for (int mf = 0; mf < 7; ++mf)
#pragma unroll
    for (int r = 0; r < 4; ++r) {
      int pl = mf * 16 + quad * 4 + r;                 // pixel within 112-tile
      int m = nb * HW + rowblk * 112 + pl;
      bf16* dst = o2 + (size_t)m * CB;
#pragma unroll
      for (int ni = 0; ni < 2; ++ni) {
        int n = nb0 + ni * 16 + l16;
        dst[n] = (bf16)fmaxf(acc[mf][ni][r] * sv[ni] + bv[ni], 0.f);
      }
    }
}

// ---------------- conv3g: y[nb][co][p] = s3*o2[p][:]·w3[co][:]+b3 (bf16, no relu,
// no residual — those move to k_resid). y layout == out layout (NCHW linear).
__global__ __launch_bounds__(256, 2) void k_conv3g(const bf16* __restrict__ o2,
                                                   const bf16* __restrict__ w3,
                                                   const float* __restrict__ s3,
                                                   const float* __restrict__ b3,
                                                   bf16* __restrict__ y) {
  __shared__ char smem[32768];
  char* const As = smem;
  char* const Bs = smem + 16384;
  const int tid = threadIdx.x, wave = tid >> 6, lane = tid & 63;
  const int quad = lane >> 4, l16 = lane & 15;
  const int wr = wave >> 1, wc = wave & 1;
  const int Mt = blockIdx.x, Nt = blockIdx.y, nbz = blockIdx.z;

  const bf16* gb[8];
  char* lb;
  if (wave < 2) {
    lb = As + wave * 8192;
#pragma unroll
    for (int i = 0; i < 8; ++i) {
      int g = wave * 8 + i;
      int m = Mt * 128 + (g >> 1) * 16 + l16;               // co < 1024
      gb[i] = w3 + (size_t)m * CB + ((g & 1) * 4 + quad) * 8;
    }
  } else {
    lb = Bs + (wave - 2) * 8192;
#pragma unroll
    for (int i = 0; i < 8; ++i) {
      int g = (wave - 2) * 8 + i;
      int p = Nt * 128 + (g >> 1) * 16 + l16;
      int pc = min(p, HW - 1);                              // clamp; never stored
      gb[i] = o2 + ((size_t)nbz * HW + pc) * CB + ((g & 1) * 4 + quad) * 8;
    }
  }

  f32x4 acc[4][4];
#pragma unroll
  for (int i = 0; i < 4; ++i)
#pragma unroll
    for (int j = 0; j < 4; ++j) acc[i][j] = {0.f, 0.f, 0.f, 0.f};

  const int lo = lane * 16;
  for (int s = 0; s < CB / 64; ++s) {
#pragma unroll
    for (int i = 0; i < 8; ++i) gl16(gb[i] + s * 64, lb + i * 1024);
    __syncthreads();
    GEMM_COMPUTE();
    __syncthreads();
  }

#pragma unroll
  for (int mi = 0; mi < 4; ++mi)
#pragma unroll
    for (int r = 0; r < 4; ++r) {
      int m = Mt * 128 + wr * 64 + mi * 16 + quad * 4 + r;  // co
      float sv = s3[m], bvv = b3[m];
      bf16* yr = y + ((size_t)nbz * COUT + m) * HW;
#pragma unroll
      for (int ni = 0; ni < 4; ++ni) {
        int n = Nt * 128 + wc * 64 + ni * 16 + l16;
        if (n < HW) yr[n] = (bf16)(acc[mi][ni][r] * sv + bvv);
      }
    }
}

extern "C" void kernel_launch(void* const* d_in, const int* in_sizes, int n_in,
                              void* d_out, int out_size, void* d_ws, size_t ws_size,
                              hipStream_t stream) {
  const float* x  = (const float*)d_in[0];
  const float* w1 = (const float*)d_in[1];
  const float* w2 = (const float*)d_in[2];
  const float* w3 = (const float*)d_in[3];
  const float* s1 = (const float*)d_in[4];
  const float* b1 = (const float*)d_in[5];
  const float* s2 = (const float*)d_in[6];
  const float* b2 = (const float*)d_in[7];
  const float* s3 = (const float*)d_in[8];
  const float* b3 = (const float*)d_in[9];
  float* out = (float*)d_out;

  char* ws = (char*)d_ws;
  // layout (bytes):
  //   xT/o2 share [0, 51,380,224) — xT dead before conv2 writes o2 (o2 = 12.8 MB at 0).
  //   y (bf16, out-linearized, 51,380,224 B) at 12,845,056 — overlaps o1p region,
  //     but o1p is dead after conv2 and y is written by conv3g (after conv2).
  //   o1p (padded bf16 NHWC 32x900x256) at 51,380,224 (14,745,600 B)
  //   w2r at 66,125,824 (1,179,648) | w1b at 67,305,472 (524,288) | w3b at 67,829,760 (524,288)
  bf16* xT  = (bf16*)(ws);
  bf16* o2  = (bf16*)(ws);
  bf16* y   = (bf16*)(ws + 12845056);
  bf16* o1p = (bf16*)(ws + 51380224);
  bf16* w2r = (bf16*)(ws + 66125824);
  bf16* w1b = (bf16*)(ws + 67305472);
  bf16* w3b = (bf16*)(ws + 67829760);

  k_zero<<<dim3(3600, 1, 1), 256, 0, stream>>>((uint4*)o1p, 921600);
  k_transpose<<<dim3(13, 16, NB), 256, 0, stream>>>(x, xT);
  k_w2r<<<dim3(2304, 1, 1), 256, 0, stream>>>(w2, w2r);
  k_cast<<<dim3(256, 1, 1), 256, 0, stream>>>(w1, w1b, CB * CIN);
  k_cast<<<dim3(256, 1, 1), 256, 0, stream>>>(w3, w3b, COUT * CB);
  k_conv1<<<dim3(196, 2, 1), 256, 0, stream>>>(xT, w1b, s1, b1, o1p);
  k_conv2<<<dim3(224, 2, 1), 256, 0, stream>>>(o1p, w2r, s2, b2, o2);
  k_conv3g<<<dim3(8, 7, NB), 256, 0, stream>>>(o2, w3b, s3, b3, y);
  k_resid<<<dim3(1568, 1, 1), 256, 0, stream>>>(y, x, out);
}